// Round 2
// baseline (1389.410 us; speedup 1.0000x reference)
//
#include <hip/hip_runtime.h>
#include <math.h>

#define IN_F 512
#define NH   64
#define NC   32
#define PPR_ALPHA 0.1f
#define NITER 10

// ---------------- MLP kernel 1: h = tanh(x @ w1.T), h is [N][64] ----------------
// block = 256 threads, tile = 128 nodes x 64 hidden, BK = 32
__global__ __launch_bounds__(256) void k_mlp1(const float* __restrict__ x,
                                              const float* __restrict__ w1,
                                              float* __restrict__ h, int N) {
    __shared__ float xsf[32 * 132];  // k-major: xs[k][n], stride 132 (pad for banks)
    __shared__ float wsf[32 * 68];   // k-major: ws[k][h], stride 68

    const int tid = threadIdx.x;
    const int n0  = blockIdx.x * 128;
    const int hq  = tid & 15;   // hidden quad: h = hq*4 + i
    const int nq  = tid >> 4;   // node group:  n = nq*8 + j   (nq 0..15)

    float acc[8][4];
#pragma unroll
    for (int j = 0; j < 8; ++j)
#pragma unroll
        for (int i = 0; i < 4; ++i) acc[j][i] = 0.f;

    for (int kt = 0; kt < IN_F / 32; ++kt) {
        const int k0 = kt * 32;
        __syncthreads();
        // stage x tile: 128 rows x 32 k, transposed into k-major LDS
        {
            const int f4 = tid & 7;      // which float4 in k
            const int r0 = tid >> 3;     // 0..31
#pragma unroll
            for (int q2 = 0; q2 < 4; ++q2) {
                const int r = r0 + 32 * q2;          // 0..127
                int row = n0 + r; if (row >= N) row = N - 1;
                const float4 v = *(const float4*)(x + (size_t)row * IN_F + k0 + f4 * 4);
                xsf[(f4 * 4 + 0) * 132 + r] = v.x;
                xsf[(f4 * 4 + 1) * 132 + r] = v.y;
                xsf[(f4 * 4 + 2) * 132 + r] = v.z;
                xsf[(f4 * 4 + 3) * 132 + r] = v.w;
            }
        }
        // stage w1 tile: 64 h x 32 k, transposed into k-major LDS
        {
            const int f4 = tid & 3;
            const int hh = tid >> 2;     // 0..63
#pragma unroll
            for (int q2 = 0; q2 < 2; ++q2) {
                const int kl = f4 * 4 + 16 * q2;
                const float4 v = *(const float4*)(w1 + (size_t)hh * IN_F + k0 + kl);
                wsf[(kl + 0) * 68 + hh] = v.x;
                wsf[(kl + 1) * 68 + hh] = v.y;
                wsf[(kl + 2) * 68 + hh] = v.z;
                wsf[(kl + 3) * 68 + hh] = v.w;
            }
        }
        __syncthreads();
#pragma unroll 4
        for (int k = 0; k < 32; ++k) {
            const float4 wv = *(const float4*)&wsf[k * 68 + hq * 4];
            const float4 xa = *(const float4*)&xsf[k * 132 + nq * 8];
            const float4 xb = *(const float4*)&xsf[k * 132 + nq * 8 + 4];
            const float xv[8] = {xa.x, xa.y, xa.z, xa.w, xb.x, xb.y, xb.z, xb.w};
            const float wvv[4] = {wv.x, wv.y, wv.z, wv.w};
#pragma unroll
            for (int j = 0; j < 8; ++j)
#pragma unroll
                for (int i = 0; i < 4; ++i) acc[j][i] += xv[j] * wvv[i];
        }
    }
    // tanh + store h
#pragma unroll
    for (int j = 0; j < 8; ++j) {
        const int row = n0 + nq * 8 + j;
        if (row < N) {
            float4 o;
            o.x = tanhf(acc[j][0]); o.y = tanhf(acc[j][1]);
            o.z = tanhf(acc[j][2]); o.w = tanhf(acc[j][3]);
            *(float4*)(h + (size_t)row * NH + hq * 4) = o;
        }
    }
}

// ---------------- MLP kernel 2: local = h @ w2.T, local is [N][32] ----------------
__global__ __launch_bounds__(256) void k_mlp2(const float* __restrict__ h,
                                              const float* __restrict__ w2,
                                              float* __restrict__ local, int N) {
    __shared__ float w2s[32 * 68];
    const int tid = threadIdx.x;
    {
        // stage ALL 64 floats of each of the 32 w2 rows: 512 float4s, 2 per thread
        const int c = tid >> 3, f4 = tid & 7;
        *(float4*)&w2s[c * 68 + f4 * 4] =
            *(const float4*)(w2 + c * NH + f4 * 4);
        *(float4*)&w2s[c * 68 + (f4 + 8) * 4] =
            *(const float4*)(w2 + c * NH + (f4 + 8) * 4);
    }
    __syncthreads();
    const int c = tid & 31, nl = tid >> 5;
    const int n = blockIdx.x * 8 + nl;
    if (n >= N) return;
    float acc = 0.f;
#pragma unroll
    for (int h4 = 0; h4 < NH / 4; ++h4) {
        const float4 hv = *(const float4*)(h + (size_t)n * NH + h4 * 4);
        const float4 wv = *(const float4*)&w2s[c * 68 + h4 * 4];
        acc += hv.x * wv.x + hv.y * wv.y + hv.z * wv.z + hv.w * wv.w;
    }
    local[(size_t)n * NC + c] = acc;
}

// ---------------- CSR build ----------------
__global__ __launch_bounds__(256) void k_zero(int* __restrict__ counts, int N) {
    const int i = blockIdx.x * 256 + threadIdx.x;
    if (i < N) counts[i] = 0;
}
__global__ __launch_bounds__(256) void k_hist(const int* __restrict__ rows,
                                              int* __restrict__ counts, int E) {
    const int e = blockIdx.x * 256 + threadIdx.x;
    if (e < E) atomicAdd(&counts[rows[e]], 1);
}
__global__ __launch_bounds__(256) void k_blocksum(const int* __restrict__ counts,
                                                  int* __restrict__ bsum, int N) {
    __shared__ int s[256];
    const int i = blockIdx.x * 256 + threadIdx.x;
    s[threadIdx.x] = (i < N) ? counts[i] : 0;
    __syncthreads();
    for (int off = 128; off > 0; off >>= 1) {
        if (threadIdx.x < off) s[threadIdx.x] += s[threadIdx.x + off];
        __syncthreads();
    }
    if (threadIdx.x == 0) bsum[blockIdx.x] = s[0];
}
// single block of 512 threads: exclusive-scan bsum in place, write rp[N]=total
__global__ __launch_bounds__(512) void k_scanb(int* __restrict__ bsum,
                                               int* __restrict__ rp, int NB, int N) {
    __shared__ int s[512];
    const int t = threadIdx.x;
    const int v = (t < NB) ? bsum[t] : 0;
    s[t] = v;
    __syncthreads();
    for (int off = 1; off < 512; off <<= 1) {
        const int add = (t >= off) ? s[t - off] : 0;
        __syncthreads();
        s[t] += add;
        __syncthreads();
    }
    if (t < NB) bsum[t] = s[t] - v;      // exclusive block offsets
    if (t == 511) rp[N] = s[511];        // total edge count
}
__global__ __launch_bounds__(256) void k_scan3(const int* __restrict__ counts,
                                               const int* __restrict__ bsum,
                                               int* __restrict__ rp,
                                               int* __restrict__ cursor, int N) {
    __shared__ int s[256];
    const int t = threadIdx.x;
    const int i = blockIdx.x * 256 + t;
    const int v = (i < N) ? counts[i] : 0;
    s[t] = v;
    __syncthreads();
    for (int off = 1; off < 256; off <<= 1) {
        const int add = (t >= off) ? s[t - off] : 0;
        __syncthreads();
        s[t] += add;
        __syncthreads();
    }
    if (i < N) {
        const int ex = s[t] - v + bsum[blockIdx.x];
        rp[i] = ex;
        cursor[i] = ex;
    }
}
__global__ __launch_bounds__(256) void k_scatter(const int* __restrict__ rows,
                                                 const int* __restrict__ cols,
                                                 const float* __restrict__ vals,
                                                 int* __restrict__ cursor,
                                                 int* __restrict__ cs,
                                                 float* __restrict__ vsd, int E) {
    const int e = blockIdx.x * 256 + threadIdx.x;
    if (e < E) {
        const int r = rows[e];
        const int pos = atomicAdd(&cursor[r], 1);
        cs[pos] = cols[e];
        vsd[pos] = vals[e];
    }
}

// ---------------- SpMM: out[r][c] = alpha*local[r][c] + sum_e val*p[col][c] ----------------
// 32 lanes per row (lane = class), 8 rows per 256-thread block
__global__ __launch_bounds__(256) void k_spmm(const int* __restrict__ rp,
                                              const int* __restrict__ cs,
                                              const float* __restrict__ vs,
                                              const float* __restrict__ p,
                                              const float* __restrict__ local,
                                              float* __restrict__ out, int N) {
    const int row = blockIdx.x * 8 + (threadIdx.x >> 5);
    if (row >= N) return;
    const int c = threadIdx.x & 31;
    const int e0 = rp[row], e1 = rp[row + 1];
    float a0 = PPR_ALPHA * local[(size_t)row * NC + c];
    float a1 = 0.f, a2 = 0.f, a3 = 0.f;
    int e = e0;
    for (; e + 4 <= e1; e += 4) {
        const int c0 = cs[e], c1 = cs[e + 1], c2 = cs[e + 2], c3 = cs[e + 3];
        const float v0 = vs[e], v1 = vs[e + 1], v2 = vs[e + 2], v3 = vs[e + 3];
        a0 += v0 * p[(size_t)c0 * NC + c];
        a1 += v1 * p[(size_t)c1 * NC + c];
        a2 += v2 * p[(size_t)c2 * NC + c];
        a3 += v3 * p[(size_t)c3 * NC + c];
    }
    for (; e < e1; ++e) a0 += vs[e] * p[(size_t)cs[e] * NC + c];
    out[(size_t)row * NC + c] = (a0 + a1) + (a2 + a3);
}

extern "C" void kernel_launch(void* const* d_in, const int* in_sizes, int n_in,
                              void* d_out, int out_size, void* d_ws, size_t ws_size,
                              hipStream_t stream) {
    const float* x    = (const float*)d_in[0];
    const float* w1   = (const float*)d_in[1];
    const float* w2   = (const float*)d_in[2];
    const int*   rows = (const int*)d_in[3];
    const int*   cols = (const int*)d_in[4];
    const float* vals = (const float*)d_in[5];

    const int N = in_sizes[0] / IN_F;   // 100000
    const int E = in_sizes[3];          // 3300000

    // workspace layout (bytes), region A shared between h (dead after mlp2) and CSR arrays
    auto align16 = [](size_t v) { return (v + 15) & ~(size_t)15; };
    char* ws = (char*)d_ws;
    const size_t szCsr = align16((size_t)E * 8);        // cols + vals
    const size_t szH   = align16((size_t)N * NH * 4);   // h
    const size_t szA   = (szCsr > szH) ? szCsr : szH;

    size_t off = 0;
    int*   csr_cols = (int*)(ws + 0);
    float* csr_vals = (float*)(ws + align16((size_t)E * 4));
    float* hbuf     = (float*)(ws + 0);                 // overlaps CSR region (used first)
    off = szA;
    float* localb = (float*)(ws + off); off += align16((size_t)N * NC * 4);
    float* pbuf   = (float*)(ws + off); off += align16((size_t)N * NC * 4);
    int*   counts = (int*)(ws + off);   off += align16((size_t)N * 4);
    int*   rp     = (int*)(ws + off);   off += align16((size_t)(N + 1) * 4);
    int*   cursor = (int*)(ws + off);   off += align16((size_t)N * 4);
    int*   bsum   = (int*)(ws + off);   off += align16((size_t)512 * 4);
    (void)ws_size; (void)n_in; (void)out_size;

    const int NB = (N + 255) / 256;     // 391 (<=512 required by k_scanb)

    // MLP: h then local  (must finish before CSR scatter overwrites region A)
    k_mlp1<<<(N + 127) / 128, 256, 0, stream>>>(x, w1, hbuf, N);
    k_mlp2<<<(N + 7) / 8, 256, 0, stream>>>(hbuf, w2, localb, N);

    // CSR build
    k_zero<<<NB, 256, 0, stream>>>(counts, N);
    k_hist<<<(E + 255) / 256, 256, 0, stream>>>(rows, counts, E);
    k_blocksum<<<NB, 256, 0, stream>>>(counts, bsum, N);
    k_scanb<<<1, 512, 0, stream>>>(bsum, rp, NB, N);
    k_scan3<<<NB, 256, 0, stream>>>(counts, bsum, rp, cursor, N);
    k_scatter<<<(E + 255) / 256, 256, 0, stream>>>(rows, cols, vals, cursor,
                                                   csr_cols, csr_vals, E);

    // 10 power iterations, ping-pong between pbuf and d_out (iter 10 -> d_out)
    float* outp = (float*)d_out;
    const int spmm_grid = (N + 7) / 8;
    for (int it = 1; it <= NITER; ++it) {
        const float* src = (it == 1) ? localb : ((it & 1) ? outp : pbuf);
        float*       dst = (it & 1) ? pbuf : outp;
        k_spmm<<<spmm_grid, 256, 0, stream>>>(rp, csr_cols, csr_vals, src, localb, dst, N);
    }
}

// Round 3
// 1275.528 us; speedup vs baseline: 1.0893x; 1.0893x over previous
//
#include <hip/hip_runtime.h>
#include <math.h>

#define IN_F 512
#define NH   64
#define NC   32
#define PPR_ALPHA 0.1f
#define NITER 10

// ---------------- MLP kernel 1: h = tanh(x @ w1.T), h is [N][64] ----------------
__global__ __launch_bounds__(256) void k_mlp1(const float* __restrict__ x,
                                              const float* __restrict__ w1,
                                              float* __restrict__ h, int N) {
    __shared__ float xsf[32 * 132];  // k-major: xs[k][n]
    __shared__ float wsf[32 * 68];   // k-major: ws[k][h]

    const int tid = threadIdx.x;
    const int n0  = blockIdx.x * 128;
    const int hq  = tid & 15;
    const int nq  = tid >> 4;

    float acc[8][4];
#pragma unroll
    for (int j = 0; j < 8; ++j)
#pragma unroll
        for (int i = 0; i < 4; ++i) acc[j][i] = 0.f;

    for (int kt = 0; kt < IN_F / 32; ++kt) {
        const int k0 = kt * 32;
        __syncthreads();
        {
            const int f4 = tid & 7;
            const int r0 = tid >> 3;
#pragma unroll
            for (int q2 = 0; q2 < 4; ++q2) {
                const int r = r0 + 32 * q2;
                int row = n0 + r; if (row >= N) row = N - 1;
                const float4 v = *(const float4*)(x + (size_t)row * IN_F + k0 + f4 * 4);
                xsf[(f4 * 4 + 0) * 132 + r] = v.x;
                xsf[(f4 * 4 + 1) * 132 + r] = v.y;
                xsf[(f4 * 4 + 2) * 132 + r] = v.z;
                xsf[(f4 * 4 + 3) * 132 + r] = v.w;
            }
        }
        {
            const int f4 = tid & 3;
            const int hh = tid >> 2;
#pragma unroll
            for (int q2 = 0; q2 < 2; ++q2) {
                const int kl = f4 * 4 + 16 * q2;
                const float4 v = *(const float4*)(w1 + (size_t)hh * IN_F + k0 + kl);
                wsf[(kl + 0) * 68 + hh] = v.x;
                wsf[(kl + 1) * 68 + hh] = v.y;
                wsf[(kl + 2) * 68 + hh] = v.z;
                wsf[(kl + 3) * 68 + hh] = v.w;
            }
        }
        __syncthreads();
#pragma unroll 4
        for (int k = 0; k < 32; ++k) {
            const float4 wv = *(const float4*)&wsf[k * 68 + hq * 4];
            const float4 xa = *(const float4*)&xsf[k * 132 + nq * 8];
            const float4 xb = *(const float4*)&xsf[k * 132 + nq * 8 + 4];
            const float xv[8] = {xa.x, xa.y, xa.z, xa.w, xb.x, xb.y, xb.z, xb.w};
            const float wvv[4] = {wv.x, wv.y, wv.z, wv.w};
#pragma unroll
            for (int j = 0; j < 8; ++j)
#pragma unroll
                for (int i = 0; i < 4; ++i) acc[j][i] += xv[j] * wvv[i];
        }
    }
#pragma unroll
    for (int j = 0; j < 8; ++j) {
        const int row = n0 + nq * 8 + j;
        if (row < N) {
            float4 o;
            o.x = tanhf(acc[j][0]); o.y = tanhf(acc[j][1]);
            o.z = tanhf(acc[j][2]); o.w = tanhf(acc[j][3]);
            *(float4*)(h + (size_t)row * NH + hq * 4) = o;
        }
    }
}

// ---------------- MLP kernel 2: local = h @ w2.T ----------------
__global__ __launch_bounds__(256) void k_mlp2(const float* __restrict__ h,
                                              const float* __restrict__ w2,
                                              float* __restrict__ local, int N) {
    __shared__ float w2s[32 * 68];
    const int tid = threadIdx.x;
    {
        const int c = tid >> 3, f4 = tid & 7;
        *(float4*)&w2s[c * 68 + f4 * 4]       = *(const float4*)(w2 + c * NH + f4 * 4);
        *(float4*)&w2s[c * 68 + (f4 + 8) * 4] = *(const float4*)(w2 + c * NH + (f4 + 8) * 4);
    }
    __syncthreads();
    const int c = tid & 31, nl = tid >> 5;
    const int n = blockIdx.x * 8 + nl;
    if (n >= N) return;
    float acc = 0.f;
#pragma unroll
    for (int h4 = 0; h4 < NH / 4; ++h4) {
        const float4 hv = *(const float4*)(h + (size_t)n * NH + h4 * 4);
        const float4 wv = *(const float4*)&w2s[c * 68 + h4 * 4];
        acc += hv.x * wv.x + hv.y * wv.y + hv.z * wv.z + hv.w * wv.w;
    }
    local[(size_t)n * NC + c] = acc;
}

// ---------------- CSR build ----------------
__global__ __launch_bounds__(256) void k_zero(int* __restrict__ counts, int N) {
    const int i = blockIdx.x * 256 + threadIdx.x;
    if (i < N) counts[i] = 0;
}
__global__ __launch_bounds__(256) void k_hist(const int* __restrict__ rows,
                                              int* __restrict__ counts, int E) {
    const int e = blockIdx.x * 256 + threadIdx.x;
    if (e < E) atomicAdd(&counts[rows[e]], 1);
}
__global__ __launch_bounds__(256) void k_blocksum(const int* __restrict__ counts,
                                                  int* __restrict__ bsum, int N) {
    __shared__ int s[256];
    const int i = blockIdx.x * 256 + threadIdx.x;
    s[threadIdx.x] = (i < N) ? counts[i] : 0;
    __syncthreads();
    for (int off = 128; off > 0; off >>= 1) {
        if (threadIdx.x < off) s[threadIdx.x] += s[threadIdx.x + off];
        __syncthreads();
    }
    if (threadIdx.x == 0) bsum[blockIdx.x] = s[0];
}
__global__ __launch_bounds__(512) void k_scanb(int* __restrict__ bsum,
                                               int* __restrict__ rp, int NB, int N) {
    __shared__ int s[512];
    const int t = threadIdx.x;
    const int v = (t < NB) ? bsum[t] : 0;
    s[t] = v;
    __syncthreads();
    for (int off = 1; off < 512; off <<= 1) {
        const int add = (t >= off) ? s[t - off] : 0;
        __syncthreads();
        s[t] += add;
        __syncthreads();
    }
    if (t < NB) bsum[t] = s[t] - v;
    if (t == 511) rp[N] = s[511];
}
__global__ __launch_bounds__(256) void k_scan3(const int* __restrict__ counts,
                                               const int* __restrict__ bsum,
                                               int* __restrict__ rp,
                                               int* __restrict__ cursor, int N) {
    __shared__ int s[256];
    const int t = threadIdx.x;
    const int i = blockIdx.x * 256 + t;
    const int v = (i < N) ? counts[i] : 0;
    s[t] = v;
    __syncthreads();
    for (int off = 1; off < 256; off <<= 1) {
        const int add = (t >= off) ? s[t - off] : 0;
        __syncthreads();
        s[t] += add;
        __syncthreads();
    }
    if (i < N) {
        const int ex = s[t] - v + bsum[blockIdx.x];
        rp[i] = ex;
        cursor[i] = ex;
    }
}
// interleaved (col, val_bits) single 8B store per edge
__global__ __launch_bounds__(256) void k_scatter(const int* __restrict__ rows,
                                                 const int* __restrict__ cols,
                                                 const float* __restrict__ vals,
                                                 int* __restrict__ cursor,
                                                 int2* __restrict__ eb, int E) {
    const int e = blockIdx.x * 256 + threadIdx.x;
    if (e < E) {
        const int r = rows[e];
        const int pos = atomicAdd(&cursor[r], 1);
        eb[pos] = make_int2(cols[e], __float_as_int(vals[e]));
    }
}

// ---------------- SpMM: out[r][:] = alpha*local[r][:] + sum_e val*p[col][:] ----------------
// 32-lane group per row; lane = (edge slot g = lane>>3, class quad q = lane&7).
// Each iteration processes 8 edges (2 slots of 4); each lane gathers float4 of p.
__global__ __launch_bounds__(256) void k_spmm(const int* __restrict__ rp,
                                              const int2* __restrict__ eb,
                                              const float* __restrict__ p,
                                              const float* __restrict__ local,
                                              float* __restrict__ out, int N) {
    const int row = blockIdx.x * 8 + (threadIdx.x >> 5);
    if (row >= N) return;
    const int lane = threadIdx.x & 31;
    const int g = lane >> 3;     // 0..3
    const int q = lane & 7;      // 0..7
    const int e0 = rp[row], e1 = rp[row + 1];

    float4 accA = {0.f, 0.f, 0.f, 0.f};
    float4 accB = {0.f, 0.f, 0.f, 0.f};
    const int nIter = (e1 - e0 + 7) >> 3;
    for (int it = 0; it < nIter; ++it) {
        const int eA = e0 + it * 8 + g;
        const int eB = eA + 4;
        const int2 evA = eb[(eA < e1) ? eA : (e1 - 1)];
        const int2 evB = eb[(eB < e1) ? eB : (e1 - 1)];
        const float4 pA = *(const float4*)(p + (size_t)evA.x * NC + q * 4);
        const float4 pB = *(const float4*)(p + (size_t)evB.x * NC + q * 4);
        const float vA = (eA < e1) ? __int_as_float(evA.y) : 0.f;
        const float vB = (eB < e1) ? __int_as_float(evB.y) : 0.f;
        accA.x += vA * pA.x; accA.y += vA * pA.y; accA.z += vA * pA.z; accA.w += vA * pA.w;
        accB.x += vB * pB.x; accB.y += vB * pB.y; accB.z += vB * pB.z; accB.w += vB * pB.w;
    }
    float4 acc;
    acc.x = accA.x + accB.x; acc.y = accA.y + accB.y;
    acc.z = accA.z + accB.z; acc.w = accA.w + accB.w;
    // reduce across the 4 edge slots (lanes stride 8, within the 32-lane group)
#pragma unroll
    for (int mask = 8; mask <= 16; mask <<= 1) {
        acc.x += __shfl_xor(acc.x, mask);
        acc.y += __shfl_xor(acc.y, mask);
        acc.z += __shfl_xor(acc.z, mask);
        acc.w += __shfl_xor(acc.w, mask);
    }
    if (g == 0) {  // lanes 0..7: q == lane
        const float4 lv = *(const float4*)(local + (size_t)row * NC + q * 4);
        acc.x += PPR_ALPHA * lv.x; acc.y += PPR_ALPHA * lv.y;
        acc.z += PPR_ALPHA * lv.z; acc.w += PPR_ALPHA * lv.w;
        *(float4*)(out + (size_t)row * NC + q * 4) = acc;
    }
}

extern "C" void kernel_launch(void* const* d_in, const int* in_sizes, int n_in,
                              void* d_out, int out_size, void* d_ws, size_t ws_size,
                              hipStream_t stream) {
    const float* x    = (const float*)d_in[0];
    const float* w1   = (const float*)d_in[1];
    const float* w2   = (const float*)d_in[2];
    const int*   rows = (const int*)d_in[3];
    const int*   cols = (const int*)d_in[4];
    const float* vals = (const float*)d_in[5];

    const int N = in_sizes[0] / IN_F;   // 100000
    const int E = in_sizes[3];          // 3300000

    auto align16 = [](size_t v) { return (v + 15) & ~(size_t)15; };
    char* ws = (char*)d_ws;
    const size_t szEdges = align16((size_t)E * 8);       // interleaved int2 edges
    const size_t szH     = align16((size_t)N * NH * 4);  // h
    const size_t szA     = (szEdges > szH) ? szEdges : szH;

    int2*  edges = (int2*)(ws + 0);
    float* hbuf  = (float*)(ws + 0);        // overlaps edges (h is dead before scatter)
    size_t off = szA;
    float* localb = (float*)(ws + off); off += align16((size_t)N * NC * 4);
    float* pbuf   = (float*)(ws + off); off += align16((size_t)N * NC * 4);
    int*   counts = (int*)(ws + off);   off += align16((size_t)N * 4);
    int*   rp     = (int*)(ws + off);   off += align16((size_t)(N + 1) * 4);
    int*   cursor = (int*)(ws + off);   off += align16((size_t)N * 4);
    int*   bsum   = (int*)(ws + off);   off += align16((size_t)512 * 4);
    (void)ws_size; (void)n_in; (void)out_size;

    const int NB = (N + 255) / 256;

    k_mlp1<<<(N + 127) / 128, 256, 0, stream>>>(x, w1, hbuf, N);
    k_mlp2<<<(N + 7) / 8, 256, 0, stream>>>(hbuf, w2, localb, N);

    k_zero<<<NB, 256, 0, stream>>>(counts, N);
    k_hist<<<(E + 255) / 256, 256, 0, stream>>>(rows, counts, E);
    k_blocksum<<<NB, 256, 0, stream>>>(counts, bsum, N);
    k_scanb<<<1, 512, 0, stream>>>(bsum, rp, NB, N);
    k_scan3<<<NB, 256, 0, stream>>>(counts, bsum, rp, cursor, N);
    k_scatter<<<(E + 255) / 256, 256, 0, stream>>>(rows, cols, vals, cursor, edges, E);

    float* outp = (float*)d_out;
    const int spmm_grid = (N + 7) / 8;
    for (int it = 1; it <= NITER; ++it) {
        const float* src = (it == 1) ? localb : ((it & 1) ? outp : pbuf);
        float*       dst = (it & 1) ? pbuf : outp;
        k_spmm<<<spmm_grid, 256, 0, stream>>>(rp, edges, src, localb, dst, N);
    }
}